// Round 1
// baseline (2383.650 us; speedup 1.0000x reference)
//
#include <hip/hip_runtime.h>
#include <math.h>

#define HP 256          // padded hidden dim (real 250)
#define PB 8            // points per workgroup
#define PW 2            // points per wave
#define STRIDE 260      // floats per LDS slot row (260*4 B, 16B-aligned)
#define NSLOT (PB*7)
#define NLAYER 6

// ws layout (float offsets)
#define WS_WH   0                        // Wp_h[6][256][256]
#define WS_WI   (6*HP*HP)                // Wi_pad[3][256]
#define WS_BI   (WS_WI + 3*HP)           // b_in_pad[256]
#define WS_BH   (WS_BI + HP)             // bh_pad[6][256]
#define WS_WO   (WS_BH + NLAYER*HP)      // Wout_pad[256][4]
#define WS_TOT  (WS_WO + HP*4)

struct alignas(16) F4 { float v[4]; };

__device__ __forceinline__ float fast_tanh(float x) {
    float e = __expf(2.0f * x);                 // overflow -> inf -> tanh -> 1 (ok)
    return 1.0f - __fdividef(2.0f, e + 1.0f);   // x<<0: e->0 -> -1 (ok)
}

__global__ void prep_kernel(const float* __restrict__ W_in, const float* __restrict__ b_in,
                            const float* __restrict__ W_h,  const float* __restrict__ b_h,
                            const float* __restrict__ W_out, float* __restrict__ ws)
{
    int i0 = blockIdx.x * blockDim.x + threadIdx.x;
    int stride = gridDim.x * blockDim.x;
    for (int i = i0; i < WS_TOT; i += stride) {
        float val = 0.0f;
        if (i < WS_WI) {
            int l = i >> 16, rem = i & 0xFFFF, k = rem >> 8, j = rem & 255;
            if (k < 250 && j < 250) val = W_h[(l*250 + k)*250 + j];
        } else if (i < WS_BI) {
            int idx = i - WS_WI; int r = idx >> 8, j = idx & 255;
            if (j < 250) val = W_in[r*250 + j];
        } else if (i < WS_BH) {
            int j = i - WS_BI;
            if (j < 250) val = b_in[j];
        } else if (i < WS_WO) {
            int idx = i - WS_BH; int l = idx >> 8, j = idx & 255;
            if (j < 250) val = b_h[l*250 + j];
        } else {
            int idx = i - WS_WO; int k = idx >> 2, o = idx & 3;
            if (k < 250) val = W_out[k*4 + o];
        }
        ws[i] = val;
    }
}

// channels: 0=val 1=d/dx 2=d/dy 3=d/dt 4=d2/dx2 5=d2/dy2 6=d2/dxdy
__launch_bounds__(256, 2)
__global__ void pinn_fused(const float* __restrict__ xg, const float* __restrict__ yg,
                           const float* __restrict__ tg, const float* __restrict__ ws,
                           const float* __restrict__ b_out, const float* __restrict__ act,
                           float* __restrict__ out, int N)
{
    __shared__ float h_lds[NSLOT * STRIDE];   // [slot = pl*7+c][k]
    __shared__ float zo_lds[PB][28];

    const int tid  = threadIdx.x;
    const int w    = tid >> 6;
    const int lane = tid & 63;
    const int j0   = lane << 2;               // this lane's 4 output neurons

    const float* __restrict__ Wh = ws + WS_WH;
    const float* __restrict__ Wi = ws + WS_WI;
    const float* __restrict__ bi = ws + WS_BI;
    const float* __restrict__ bh = ws + WS_BH;
    const float* __restrict__ Wo = ws + WS_WO;

    F4 st[7][PW];

    // ---------------- input layer ----------------
    {
        F4 wi0 = *reinterpret_cast<const F4*>(Wi + 0*HP + j0);
        F4 wi1 = *reinterpret_cast<const F4*>(Wi + 1*HP + j0);
        F4 wi2 = *reinterpret_cast<const F4*>(Wi + 2*HP + j0);
        F4 bin = *reinterpret_cast<const F4*>(bi + j0);
        float c0 = 10.0f * act[0];
        #pragma unroll
        for (int p = 0; p < PW; ++p) {
            int gp = blockIdx.x * PB + w*PW + p;
            gp = gp < N ? gp : N - 1;
            float px = xg[gp], py = yg[gp], pt = tg[gp];
            #pragma unroll
            for (int r = 0; r < 4; ++r) {
                float W0 = wi0.v[r], W1 = wi1.v[r], W2 = wi2.v[r];
                float z = px*W0 + py*W1 + pt*W2 + bin.v[r];
                float y = fast_tanh(c0 * z);
                float s = 1.0f - y*y;
                float cs = c0 * s;
                float m2 = -2.0f * c0 * cs * y;    // = -2 c^2 y sech^2
                st[0][p].v[r] = y;
                st[1][p].v[r] = cs*W0;
                st[2][p].v[r] = cs*W1;
                st[3][p].v[r] = cs*W2;
                st[4][p].v[r] = m2*W0*W0;          // z_xx = 0 at input
                st[5][p].v[r] = m2*W1*W1;
                st[6][p].v[r] = m2*W0*W1;
            }
        }
        #pragma unroll
        for (int c = 0; c < 7; ++c)
            #pragma unroll
            for (int p = 0; p < PW; ++p)
                *reinterpret_cast<F4*>(&h_lds[((w*PW+p)*7 + c)*STRIDE + j0]) = st[c][p];
    }

    // ---------------- hidden layers ----------------
    for (int L = 0; L < NLAYER; ++L) {
        __syncthreads();   // orders prior LDS writes before this layer's broadcast reads
        const float* __restrict__ W = Wh + L*HP*HP;
        F4 bhv = *reinterpret_cast<const F4*>(bh + L*HP + j0);
        F4 acc[7][PW];
        #pragma unroll
        for (int c = 0; c < 7; ++c)
            #pragma unroll
            for (int p = 0; p < PW; ++p)
                #pragma unroll
                for (int r = 0; r < 4; ++r)
                    acc[c][p].v[r] = (c == 0) ? bhv.v[r] : 0.0f;

        #pragma unroll 2
        for (int kq = 0; kq < HP/4; ++kq) {
            F4 w0 = *reinterpret_cast<const F4*>(W + (kq*4+0)*HP + j0);
            F4 w1 = *reinterpret_cast<const F4*>(W + (kq*4+1)*HP + j0);
            F4 w2 = *reinterpret_cast<const F4*>(W + (kq*4+2)*HP + j0);
            F4 w3 = *reinterpret_cast<const F4*>(W + (kq*4+3)*HP + j0);
            #pragma unroll
            for (int c = 0; c < 7; ++c) {
                #pragma unroll
                for (int p = 0; p < PW; ++p) {
                    F4 hv = *reinterpret_cast<const F4*>(
                                &h_lds[((w*PW+p)*7 + c)*STRIDE + kq*4]);  // wave-uniform broadcast
                    #pragma unroll
                    for (int r = 0; r < 4; ++r)
                        acc[c][p].v[r] += hv.v[0]*w0.v[r] + hv.v[1]*w1.v[r]
                                        + hv.v[2]*w2.v[r] + hv.v[3]*w3.v[r];
                }
            }
        }

        float cc = 10.0f * act[L+1];
        #pragma unroll
        for (int p = 0; p < PW; ++p)
            #pragma unroll
            for (int r = 0; r < 4; ++r) {
                float z   = acc[0][p].v[r];
                float zx  = acc[1][p].v[r], zy = acc[2][p].v[r], zt = acc[3][p].v[r];
                float zxx = acc[4][p].v[r], zyy = acc[5][p].v[r], zxy = acc[6][p].v[r];
                float y = fast_tanh(cc * z);
                float s = 1.0f - y*y;
                float cs = cc * s;
                float m2 = -2.0f * cc * cs * y;
                acc[0][p].v[r] = y;
                acc[1][p].v[r] = cs*zx;
                acc[2][p].v[r] = cs*zy;
                acc[3][p].v[r] = cs*zt;
                acc[4][p].v[r] = cs*zxx + m2*zx*zx;
                acc[5][p].v[r] = cs*zyy + m2*zy*zy;
                acc[6][p].v[r] = cs*zxy + m2*zx*zy;
            }
        __syncthreads();   // keep reads (above) strictly before overwrite (below)
        #pragma unroll
        for (int c = 0; c < 7; ++c)
            #pragma unroll
            for (int p = 0; p < PW; ++p)
                *reinterpret_cast<F4*>(&h_lds[((w*PW+p)*7 + c)*STRIDE + j0]) = acc[c][p];
    }

    // ---------------- output layer: 28 dots per point ----------------
    __syncthreads();
    if (tid < PB*28) {
        int pl = tid / 28, idx = tid % 28;
        int c = idx >> 2, o = idx & 3;
        const float* hrow = &h_lds[(pl*7 + c)*STRIDE];
        float s = 0.0f;
        for (int k = 0; k < HP; ++k)
            s += hrow[k] * Wo[k*4 + o];
        zo_lds[pl][idx] = s;
    }
    __syncthreads();

    // ---------------- heads + PDE residuals (1 thread per point) ----------------
    if (tid < PB) {
        int gp = blockIdx.x * PB + tid;
        if (gp < N) {
            float zc[7][4];
            #pragma unroll
            for (int c = 0; c < 7; ++c)
                #pragma unroll
                for (int o = 0; o < 4; ++o)
                    zc[c][o] = zo_lds[tid][c*4 + o] + (c == 0 ? b_out[o] : 0.0f);

            float u  = zc[0][0], vv = zc[0][1];
            float u_x = zc[1][0], u_y = zc[2][0], u_t = zc[3][0];
            float u_xx = zc[4][0], u_yy = zc[5][0];
            float v_x = zc[1][1], v_y = zc[2][1], v_t = zc[3][1];
            float v_xx = zc[4][1], v_yy = zc[5][1];

            float ep  = expf(zc[0][2]);
            float p_x = ep * zc[1][2], p_y = ep * zc[2][2];

            float a   = 1.0f / (1.0f + expf(-zc[0][3]));
            float sp  = a * (1.0f - a);
            float spp = sp * (1.0f - 2.0f*a);
            float z1a = zc[1][3], z2a = zc[2][3];
            float a_x = sp * z1a, a_y = sp * z2a, a_t = sp * zc[3][3];
            float a_xx = spp*z1a*z1a + sp*zc[4][3];
            float a_yy = spp*z2a*z2a + sp*zc[5][3];
            float a_xy = spp*z1a*z2a + sp*zc[6][3];

            float mu   = 10.0f - 9.0f*a;          // MU2 + (MU1-MU2) a
            float mu_x = -9.0f*a_x, mu_y = -9.0f*a_y;
            float rr   = 1.0f - 0.9f*a;           // rho / RHO_REF
            float g  = sqrtf(a_x*a_x + a_y*a_y + 2.220446049250313e-16f);
            float g3 = g*g*g;
            float curv = -((a_xx + a_yy)/g
                         - (a_x*a_x*a_xx + a_y*a_y*a_yy + 2.0f*a_x*a_y*a_xy)/g3);
            float one_Re   = mu   * 0.002f;       // /RE_DEN(=500)
            float one_Re_x = mu_x * 0.002f;
            float one_Re_y = mu_y * 0.002f;

            float PDE_m = u_x + v_y;
            float PDE_a = a_t + u*a_x + vv*a_y;
            float PDE_u = (u_t + u*u_x + vv*u_y)*rr + p_x - 0.049f*curv*a_x
                        - one_Re*(u_xx + u_yy) - 2.0f*one_Re_x*u_x - one_Re_y*(u_y + v_x);
            float PDE_v = (v_t + u*v_x + vv*v_y)*rr + p_y - 0.049f*curv*a_y
                        - one_Re*(v_xx + v_yy) - rr*0.49f
                        - 2.0f*one_Re_y*v_y - one_Re_x*(u_y + v_x);

            out[0*N + gp] = PDE_m;
            out[1*N + gp] = PDE_u;
            out[2*N + gp] = PDE_v;
            out[3*N + gp] = PDE_a;
        }
    }
}

extern "C" void kernel_launch(void* const* d_in, const int* in_sizes, int n_in,
                              void* d_out, int out_size, void* d_ws, size_t ws_size,
                              hipStream_t stream)
{
    const float* x     = (const float*)d_in[0];
    const float* y     = (const float*)d_in[1];
    const float* t     = (const float*)d_in[2];
    const float* W_in  = (const float*)d_in[3];
    const float* b_in  = (const float*)d_in[4];
    const float* W_h   = (const float*)d_in[5];
    const float* b_h   = (const float*)d_in[6];
    const float* W_out = (const float*)d_in[7];
    const float* b_out = (const float*)d_in[8];
    const float* act   = (const float*)d_in[9];
    float* ws  = (float*)d_ws;
    float* out = (float*)d_out;
    int N = in_sizes[0];

    hipLaunchKernelGGL(prep_kernel, dim3(512), dim3(256), 0, stream,
                       W_in, b_in, W_h, b_h, W_out, ws);
    int nb = (N + PB - 1) / PB;
    hipLaunchKernelGGL(pinn_fused, dim3(nb), dim3(256), 0, stream,
                       x, y, t, ws, b_out, act, out, N);
}

// Round 2
// 1492.894 us; speedup vs baseline: 1.5967x; 1.5967x over previous
//
#include <hip/hip_runtime.h>
#include <math.h>
#include <stdint.h>

#define HP 256
#define PTS 8                 // points per workgroup
#define ROWS 64               // 8 points x 8 channels (ch7 dummy)
#define ASTRIDE 260           // u32 per A row (pad: 260%32=4 -> 2-way bank alias, free)
#define NLAYER 6
#define WT_ELEMS (6*256*256)  // per hi/lo array, fp16

typedef _Float16 half8 __attribute__((ext_vector_type(8)));
typedef float   float4v __attribute__((ext_vector_type(4)));

// f32 extras section (float offsets within section)
#define C_WI 0                // [3][256]
#define C_BI 768              // [256]
#define C_BH 1024             // [6][256]
#define C_WO 2560             // [256][4]
#define C_TOT 3584

__device__ __forceinline__ float fast_tanh(float x) {
    float e = __expf(2.0f * x);
    return 1.0f - __fdividef(2.0f, e + 1.0f);
}

__device__ __forceinline__ uint32_t pack_hl(float x) {
    _Float16 h = (_Float16)x;
    float r = (x - (float)h) * 1024.0f;
    _Float16 l = (_Float16)r;
    union { _Float16 f; uint16_t u; } ch, cl;
    ch.f = h; cl.f = l;
    return (uint32_t)ch.u | ((uint32_t)cl.u << 16);
}

__device__ __forceinline__ float unpack_hl(uint32_t u) {
    union { uint16_t s; _Float16 h; } a, b;
    a.s = (uint16_t)(u & 0xffff); b.s = (uint16_t)(u >> 16);
    return (float)a.h + (float)b.h * (1.0f / 1024.0f);
}

// ---------------- prep: transpose + split weights ----------------
__global__ void prep_kernel(const float* __restrict__ W_in, const float* __restrict__ b_in,
                            const float* __restrict__ W_h,  const float* __restrict__ b_h,
                            const float* __restrict__ W_out, void* __restrict__ wsv)
{
    _Float16* wt_hi = (_Float16*)wsv;
    _Float16* wt_lo = wt_hi + WT_ELEMS;
    float* cf = (float*)((char*)wsv + (size_t)2 * WT_ELEMS * 2);

    int i0 = blockIdx.x * blockDim.x + threadIdx.x;
    int stride = gridDim.x * blockDim.x;
    for (int i = i0; i < WT_ELEMS; i += stride) {
        int l = i >> 16, n = (i >> 8) & 255, k = i & 255;
        float w = (n < 250 && k < 250) ? W_h[(l*250 + k)*250 + n] : 0.0f;  // Wt[l][n][k]=W_h[l][k][n]
        _Float16 h = (_Float16)w;
        _Float16 lo = (_Float16)((w - (float)h) * 1024.0f);
        wt_hi[i] = h; wt_lo[i] = lo;
    }
    for (int i = i0; i < C_TOT; i += stride) {
        float v = 0.0f;
        if (i < C_BI) { int r = i >> 8, j = i & 255; if (j < 250) v = W_in[r*250 + j]; }
        else if (i < C_BH) { int j = i - C_BI; if (j < 250) v = b_in[j]; }
        else if (i < C_WO) { int idx = i - C_BH; int l = idx >> 8, j = idx & 255; if (j < 250) v = b_h[l*250 + j]; }
        else { int idx = i - C_WO; int k = idx >> 2, o = idx & 3; if (k < 250) v = W_out[k*4 + o]; }
        cf[i] = v;
    }
}

// ---------------- fused PINN kernel ----------------
__launch_bounds__(256, 2)
__global__ void pinn_mfma(const float* __restrict__ xg, const float* __restrict__ yg,
                          const float* __restrict__ tg, const void* __restrict__ wsv,
                          const float* __restrict__ b_out, const float* __restrict__ act,
                          float* __restrict__ out, int N)
{
    __shared__ uint32_t Apack[ROWS * ASTRIDE];
    __shared__ float zo[PTS][28];

    const _Float16* __restrict__ wt_hi = (const _Float16*)wsv;
    const _Float16* __restrict__ wt_lo = wt_hi + WT_ELEMS;
    const float* __restrict__ cf = (const float*)((const char*)wsv + (size_t)2 * WT_ELEMS * 2);

    const int tid  = threadIdx.x;
    const int lane = tid & 63;
    const int wave = tid >> 6;
    const int rh   = wave & 1;        // row half: rows 32*rh .. +31
    const int chh  = wave >> 1;       // col half: cols 128*chh .. +127
    const int q    = lane >> 4;       // quad
    const int j16  = lane & 15;

    // ---------- input layer jet: thread tid handles neuron j = tid for all 8 points ----------
    {
        int j = tid;
        float wi0 = cf[C_WI + j], wi1 = cf[C_WI + 256 + j], wi2 = cf[C_WI + 512 + j];
        float biv = cf[C_BI + j];
        float c0 = 10.0f * act[0];
        #pragma unroll
        for (int p = 0; p < PTS; ++p) {
            int gp = blockIdx.x * PTS + p;
            gp = gp < N ? gp : N - 1;
            float px = xg[gp], py = yg[gp], pt = tg[gp];
            float z = px*wi0 + py*wi1 + pt*wi2 + biv;
            float y = fast_tanh(c0 * z);
            float s = 1.0f - y*y;
            float cs = c0 * s;
            float m2 = -2.0f * c0 * cs * y;
            uint32_t* r = &Apack[(8*p) * ASTRIDE + j];
            r[0*ASTRIDE] = pack_hl(y);
            r[1*ASTRIDE] = pack_hl(cs*wi0);
            r[2*ASTRIDE] = pack_hl(cs*wi1);
            r[3*ASTRIDE] = pack_hl(cs*wi2);
            r[4*ASTRIDE] = pack_hl(m2*wi0*wi0);
            r[5*ASTRIDE] = pack_hl(m2*wi1*wi1);
            r[6*ASTRIDE] = pack_hl(m2*wi0*wi1);
            r[7*ASTRIDE] = 0u;
        }
    }

    // ---------- hidden layers ----------
    for (int L = 0; L < NLAYER; ++L) {
        float cc = 10.0f * act[L + 1];
        __syncthreads();                       // Apack stable

        // load this wave's A fragments (2 row-tiles x full K) into registers
        half8 Ahi[2][8], Alo[2][8];
        #pragma unroll
        for (int rt = 0; rt < 2; ++rt) {
            #pragma unroll
            for (int s = 0; s < 8; ++s) {
                const uint32_t* src = &Apack[(32*rh + 16*rt + j16) * ASTRIDE + 32*s + 8*q];
                uint4 pa = *(const uint4*)(src);
                uint4 pb = *(const uint4*)(src + 4);
                union { uint32_t u[4]; half8 h; } uh, ul;
                uh.u[0] = (pa.x & 0xffffu) | (pa.y << 16);
                uh.u[1] = (pa.z & 0xffffu) | (pa.w << 16);
                uh.u[2] = (pb.x & 0xffffu) | (pb.y << 16);
                uh.u[3] = (pb.z & 0xffffu) | (pb.w << 16);
                ul.u[0] = (pa.x >> 16) | (pa.y & 0xffff0000u);
                ul.u[1] = (pa.z >> 16) | (pa.w & 0xffff0000u);
                ul.u[2] = (pb.x >> 16) | (pb.y & 0xffff0000u);
                ul.u[3] = (pb.z >> 16) | (pb.w & 0xffff0000u);
                Ahi[rt][s] = uh.h;
                Alo[rt][s] = ul.h;
            }
        }
        __syncthreads();                       // all waves done reading before overwrite

        const _Float16* __restrict__ wbase_hi = wt_hi + ((size_t)L << 16);
        const _Float16* __restrict__ wbase_lo = wt_lo + ((size_t)L << 16);

        for (int t = 0; t < 8; ++t) {
            if (t && (t & 1) == 0) __syncthreads();   // keep waves lockstep for L1 reuse
            int nrow = 128*chh + 16*t + j16;          // this lane's B row (out neuron n)
            const _Float16* bp_hi = wbase_hi + (size_t)nrow * 256 + 8*q;
            const _Float16* bp_lo = wbase_lo + (size_t)nrow * 256 + 8*q;

            float4v m0 = {0.f,0.f,0.f,0.f}, m1 = {0.f,0.f,0.f,0.f};
            float4v c0v = {0.f,0.f,0.f,0.f}, c1v = {0.f,0.f,0.f,0.f};
            #pragma unroll
            for (int s = 0; s < 8; ++s) {
                half8 bh = *(const half8*)(bp_hi + 32*s);
                half8 bl = *(const half8*)(bp_lo + 32*s);
                m0  = __builtin_amdgcn_mfma_f32_16x16x32_f16(Ahi[0][s], bh, m0, 0, 0, 0);
                m1  = __builtin_amdgcn_mfma_f32_16x16x32_f16(Ahi[1][s], bh, m1, 0, 0, 0);
                c0v = __builtin_amdgcn_mfma_f32_16x16x32_f16(Ahi[0][s], bl, c0v, 0, 0, 0);
                c1v = __builtin_amdgcn_mfma_f32_16x16x32_f16(Ahi[1][s], bl, c1v, 0, 0, 0);
                c0v = __builtin_amdgcn_mfma_f32_16x16x32_f16(Alo[0][s], bh, c0v, 0, 0, 0);
                c1v = __builtin_amdgcn_mfma_f32_16x16x32_f16(Alo[1][s], bh, c1v, 0, 0, 0);
            }
            #pragma unroll
            for (int i = 0; i < 4; ++i) {
                m0[i] += c0v[i] * (1.0f/1024.0f);
                m1[i] += c1v[i] * (1.0f/1024.0f);
            }

            // ---- epilogue per row-tile: jet activation, write next A in place ----
            #pragma unroll
            for (int rt = 0; rt < 2; ++rt) {
                float4v m = rt ? m1 : m0;
                int pl = q >> 1, ql = q & 1;
                float e0 = __shfl_xor(m[0], 16);
                float e1 = __shfl_xor(m[1], 16);
                float e2 = __shfl_xor(m[2], 16);
                float z  = ql ? e0 : m[0];
                float y  = fast_tanh(cc * z);
                float sh = 1.0f - y*y;
                float cs = cc * sh;
                float o0, o1, o2, o3;
                if (!ql) {
                    o0 = y; o1 = cs*m[1]; o2 = cs*m[2]; o3 = cs*m[3];
                } else {
                    float m2c = -2.0f * cc * cs * y;
                    o0 = cs*m[0] + m2c*e1*e1;   // ch4: cs*zxx + m2*zx^2
                    o1 = cs*m[1] + m2c*e2*e2;   // ch5
                    o2 = cs*m[2] + m2c*e1*e2;   // ch6
                    o3 = 0.0f;                  // ch7 dummy
                }
                uint32_t* dst = &Apack[(32*rh + 16*rt + 8*pl + 4*ql) * ASTRIDE + 128*chh + 16*t + j16];
                dst[0*ASTRIDE] = pack_hl(o0);
                dst[1*ASTRIDE] = pack_hl(o1);
                dst[2*ASTRIDE] = pack_hl(o2);
                dst[3*ASTRIDE] = ql ? 0u : pack_hl(o3);
            }
        }
    }

    // ---------- output layer: 28 dots per point ----------
    __syncthreads();
    if (tid < PTS * 28) {
        int p = tid / 28, idx = tid % 28;
        int c = idx >> 2, o = idx & 3;
        const uint32_t* row = &Apack[(8*p + c) * ASTRIDE];
        float s = 0.0f;
        for (int k = 0; k < HP; ++k)
            s += unpack_hl(row[k]) * cf[C_WO + 4*k + o];
        zo[p][idx] = s;
    }
    __syncthreads();

    // ---------- heads + PDE residuals ----------
    if (tid < PTS) {
        int gp = blockIdx.x * PTS + tid;
        if (gp < N) {
            float zc[7][4];
            #pragma unroll
            for (int c = 0; c < 7; ++c)
                #pragma unroll
                for (int o = 0; o < 4; ++o)
                    zc[c][o] = zo[tid][c*4 + o] + (c == 0 ? b_out[o] : 0.0f);

            float u  = zc[0][0], vv = zc[0][1];
            float u_x = zc[1][0], u_y = zc[2][0], u_t = zc[3][0];
            float u_xx = zc[4][0], u_yy = zc[5][0];
            float v_x = zc[1][1], v_y = zc[2][1], v_t = zc[3][1];
            float v_xx = zc[4][1], v_yy = zc[5][1];

            float ep  = expf(zc[0][2]);
            float p_x = ep * zc[1][2], p_y = ep * zc[2][2];

            float a   = 1.0f / (1.0f + expf(-zc[0][3]));
            float sp  = a * (1.0f - a);
            float spp = sp * (1.0f - 2.0f*a);
            float z1a = zc[1][3], z2a = zc[2][3];
            float a_x = sp * z1a, a_y = sp * z2a, a_t = sp * zc[3][3];
            float a_xx = spp*z1a*z1a + sp*zc[4][3];
            float a_yy = spp*z2a*z2a + sp*zc[5][3];
            float a_xy = spp*z1a*z2a + sp*zc[6][3];

            float mu_x = -9.0f*a_x, mu_y = -9.0f*a_y;
            float mu   = 10.0f - 9.0f*a;
            float rr   = 1.0f - 0.9f*a;
            float g  = sqrtf(a_x*a_x + a_y*a_y + 2.220446049250313e-16f);
            float g3 = g*g*g;
            float curv = -((a_xx + a_yy)/g
                         - (a_x*a_x*a_xx + a_y*a_y*a_yy + 2.0f*a_x*a_y*a_xy)/g3);
            float one_Re   = mu   * 0.002f;
            float one_Re_x = mu_x * 0.002f;
            float one_Re_y = mu_y * 0.002f;

            float PDE_m = u_x + v_y;
            float PDE_a = a_t + u*a_x + vv*a_y;
            float PDE_u = (u_t + u*u_x + vv*u_y)*rr + p_x - 0.049f*curv*a_x
                        - one_Re*(u_xx + u_yy) - 2.0f*one_Re_x*u_x - one_Re_y*(u_y + v_x);
            float PDE_v = (v_t + u*v_x + vv*v_y)*rr + p_y - 0.049f*curv*a_y
                        - one_Re*(v_xx + v_yy) - rr*0.49f
                        - 2.0f*one_Re_y*v_y - one_Re_x*(u_y + v_x);

            out[0*N + gp] = PDE_m;
            out[1*N + gp] = PDE_u;
            out[2*N + gp] = PDE_v;
            out[3*N + gp] = PDE_a;
        }
    }
}

extern "C" void kernel_launch(void* const* d_in, const int* in_sizes, int n_in,
                              void* d_out, int out_size, void* d_ws, size_t ws_size,
                              hipStream_t stream)
{
    const float* x     = (const float*)d_in[0];
    const float* y     = (const float*)d_in[1];
    const float* t     = (const float*)d_in[2];
    const float* W_in  = (const float*)d_in[3];
    const float* b_in  = (const float*)d_in[4];
    const float* W_h   = (const float*)d_in[5];
    const float* b_h   = (const float*)d_in[6];
    const float* W_out = (const float*)d_in[7];
    const float* b_out = (const float*)d_in[8];
    const float* act   = (const float*)d_in[9];
    float* out = (float*)d_out;
    int N = in_sizes[0];

    hipLaunchKernelGGL(prep_kernel, dim3(512), dim3(256), 0, stream,
                       W_in, b_in, W_h, b_h, W_out, d_ws);
    int nb = (N + PTS - 1) / PTS;
    hipLaunchKernelGGL(pinn_mfma, dim3(nb), dim3(256), 0, stream,
                       x, y, t, d_ws, b_out, act, out, N);
}